// Round 7
// baseline (1531.350 us; speedup 1.0000x reference)
//
#include <hip/hip_runtime.h>

#define BB 32
#define TT 400
#define HH 512
#define NSTEP 100
#define VO 511
#define LSEQ 101
#define NBLK 256
#define NTHR 512
#define AOFF (BB*NSTEP*VO)
#define AXP 416
#define AG __HIP_MEMORY_SCOPE_AGENT
#define SPIN_CAP 20000000u

typedef float f4 __attribute__((ext_vector_type(4)));
typedef _Float16 v2h __attribute__((ext_vector_type(2)));
typedef _Float16 v8h __attribute__((ext_vector_type(8)));
typedef unsigned long long ull;

#if defined(__has_builtin)
#if __has_builtin(__builtin_amdgcn_fdot2)
#define HAVE_FDOT2 1
#endif
#endif
#ifdef HAVE_FDOT2
#define FDOT2(w, a, c) __builtin_amdgcn_fdot2((w), (a), (c), false)
#else
#define FDOT2(w, a, c) fmaf((float)(w)[0], (float)(a)[0], fmaf((float)(w)[1], (float)(a)[1], (c)))
#endif

// 8-k fdot2 block: weight v8h vs 4 activation pairs
#define DOT8(acc, wv, p0, p1, p2, p3)                      \
  acc = FDOT2((v2h{(wv)[0],(wv)[1]}), (p0), acc);          \
  acc = FDOT2((v2h{(wv)[2],(wv)[3]}), (p1), acc);          \
  acc = FDOT2((v2h{(wv)[4],(wv)[5]}), (p2), acc);          \
  acc = FDOT2((v2h{(wv)[6],(wv)[7]}), (p3), acc);

struct P {
  const float* x; const int* y; const float* emb;
  const float* wih; const float* whh; const float* bih; const float* bhh;
  const float* cw; const float* cb; const float* aw; const float* ab;
  const float* fw; const float* fb;
  float* out; int* ctrl;
  ull* hx64; ull* axt; ull* pm64; ull* pl64; ull* pacc64;
  _Float16* w16;
};

__device__ __forceinline__ float wredsum(float v) {
#pragma unroll
  for (int d = 1; d < 64; d <<= 1) v += __shfl_xor(v, d, 64);
  return v;
}
__device__ __forceinline__ unsigned f2u(float f){ union{float f;unsigned u;}c;c.f=f;return c.u; }
__device__ __forceinline__ float u2f(unsigned u){ union{unsigned u;float f;}c;c.u=u;return c.f; }
// uncached (IC coherence point) ops
__device__ __forceinline__ ull gldll(const ull* q) {
  return __hip_atomic_load(q, __ATOMIC_RELAXED, AG);
}
__device__ __forceinline__ void gstll(ull* q, ull v) {
  __hip_atomic_store(q, v, __ATOMIC_RELAXED, AG);
}
__device__ __forceinline__ ull tagw(unsigned tag, float f) {
  return ((ull)tag << 32) | (ull)f2u(f);
}

__global__ __launch_bounds__(NTHR, 2) void seq2seq_kernel(P p) {
  const int tid  = threadIdx.x;
  const int lane = tid & 63;
  const int wave = tid >> 6;
  const int blk  = blockIdx.x;
  const int b   = blk >> 3;
  const int tch = blk & 7;
  const int t0  = tch * 50;
  const int hb  = tch * 64;
  const int h0s = lane * 8;

  // ---- LDS arena 78,736 B ----
  __shared__ __align__(16) char smem[78736];
  _Float16* xhL = (_Float16*)smem;                 // 51200: x chunk fp16
  float*    hxL = (float*)(smem + 51200);          // 2048: hx(s) fp32
  _Float16* ixh = (_Float16*)(smem + 53248);       // 1024: emb+sx fp16 (doubles as Bh for FC)
  _Float16* hxh = (_Float16*)(smem + 54272);       // 1024: hx fp16
  float*    redu= (float*)(smem + 55296);          // 16384: GRU-gi/FC partials ∪ score merge
  v2h*      axp = (v2h*)(smem + 71952);            // 280
  float*    stL = (float*)(smem + 72232);          // 224
  float*    mS  = (float*)(smem + 72456);          // 32
  float*    lS  = mS + 8; float* pmL = mS + 16; float* plL = mS + 24;
  float*    ghp = (float*)(smem + 72592);          // 6144: W_hh partials [8 waves][192]

  const v8h* wiT = (const v8h*)p.w16;          // [3][64][512] ih (k-major)
  const v8h* whT = wiT + 98304;                // [3][64][512] hh
  const v8h* fwT = wiT + 196608;               // [64][512]    fc

  int* initc = p.ctrl + 8192;

  // ---- persistent conv/attn weights ----
  v2h cwp[8][8]; float cbr[8], awr[8];
#pragma unroll
  for (int j = 0; j < 8; ++j) {
    int h = h0s + j;
    cbr[j] = p.cb[h]; awr[j] = p.aw[h];
#pragma unroll
    for (int mm = 0; mm < 8; ++mm) {
      float w0 = p.cw[h*15 + 2*mm];
      float w1 = (2*mm+1 < 15) ? p.cw[h*15 + 2*mm + 1] : 0.f;
      cwp[j][mm] = v2h{(_Float16)w0, (_Float16)w1};
    }
  }
  const float atb = p.ab[0];

  // ---- one-time: transposed fp16 weight build (k-major, h-contiguous) ----
  {
    const int gthr = NBLK*NTHR;
    const int gid = blk*NTHR + tid;
    auto cvt8 = [&](const float* s8, ull* dst) {
      v8h v;
#pragma unroll
      for (int e = 0; e < 8; ++e) v[e] = (_Float16)s8[e];
      union { v8h h; ull u[2]; } c; c.h = v;
      gstll(dst, c.u[0]); gstll(dst + 1, c.u[1]);
    };
    for (int i = gid; i < 98304; i += gthr) {
      int h = i & 511, kb = (i >> 9) & 63, g = i >> 15;
      cvt8(p.wih + ((size_t)(g*512 + h))*512 + kb*8, (ull*)((v8h*)p.w16 + i));
    }
    for (int i = gid; i < 98304; i += gthr) {
      int h = i & 511, kb = (i >> 9) & 63, g = i >> 15;
      cvt8(p.whh + ((size_t)(g*512 + h))*512 + kb*8, (ull*)((v8h*)p.w16 + 98304 + i));
    }
    for (int i = gid; i < 32768; i += gthr) {
      int h = i & 511, kb = i >> 9;
      ull* dst = (ull*)((v8h*)p.w16 + 196608 + i);
      if (h < VO) cvt8(p.fw + (size_t)h*512 + kb*8, dst);
      else { gstll(dst, 0ull); gstll(dst + 1, 0ull); }
    }
  }
  for (int i = 0; i < 50; ++i)
    xhL[i*512 + tid] = (_Float16)p.x[((size_t)b*TT + t0 + i)*HH + tid];
  hxL[tid] = 0.f;
  hxh[tid] = (_Float16)0.f;
  {
    const int yb = p.y[b*LSEQ + 0];
    ixh[tid] = (_Float16)p.emb[(size_t)yb*HH + tid];
  }
  __syncthreads();
  if (tid == 0) {
    __builtin_amdgcn_s_waitcnt(0);
    __hip_atomic_fetch_add((unsigned*)initc, 1u, __ATOMIC_RELAXED, AG);
    unsigned it = 0;
    while (__hip_atomic_load((unsigned*)initc, __ATOMIC_RELAXED, AG) < (unsigned)NBLK) {
      __builtin_amdgcn_s_sleep(2);
      if (++it > SPIN_CAP) break;
    }
  }
  __syncthreads();

  // ---- GRU split halves: gh = W_hh*hx (gate-B shadow), gi = W_ih*ix (critical) ----
  auto gru_hh = [&]() {
    const int hg = hb + lane;
    const v2h* hxp = (const v2h*)hxh;
    float pr = 0.f, pz = 0.f, phn = 0.f;
#pragma unroll 2
    for (int kb = 0; kb < 8; ++kb) {
      const int kbg = wave*8 + kb;
      const int pb  = kbg*4;
      v2h c0 = hxp[pb], c1 = hxp[pb+1], c2 = hxp[pb+2], c3 = hxp[pb+3];
      v8h wrh = whT[(0*64 + kbg)*512 + hg];
      v8h wzh = whT[(1*64 + kbg)*512 + hg];
      v8h wnh = whT[(2*64 + kbg)*512 + hg];
      DOT8(pr,  wrh, c0, c1, c2, c3);
      DOT8(pz,  wzh, c0, c1, c2, c3);
      DOT8(phn, wnh, c0, c1, c2, c3);
    }
    ghp[wave*192 +   0 + lane] = pr;
    ghp[wave*192 +  64 + lane] = pz;
    ghp[wave*192 + 128 + lane] = phn;
    // no barrier: consumed after gru_gi's internal barrier
  };

  auto gru_gi = [&](int s) {
    const int hg = hb + lane;
    const v2h* ixp = (const v2h*)ixh;
    float pr = 0.f, pz = 0.f, pin = 0.f;
#pragma unroll 2
    for (int kb = 0; kb < 8; ++kb) {
      const int kbg = wave*8 + kb;
      const int pb  = kbg*4;
      v2h a0 = ixp[pb], a1 = ixp[pb+1], a2 = ixp[pb+2], a3 = ixp[pb+3];
      v8h wri = wiT[(0*64 + kbg)*512 + hg];
      v8h wzi = wiT[(1*64 + kbg)*512 + hg];
      v8h wni = wiT[(2*64 + kbg)*512 + hg];
      DOT8(pr,  wri, a0, a1, a2, a3);
      DOT8(pz,  wzi, a0, a1, a2, a3);
      DOT8(pin, wni, a0, a1, a2, a3);
    }
    redu[wave*256 +   0 + lane] = pr;
    redu[wave*256 +  64 + lane] = pz;
    redu[wave*256 + 128 + lane] = pin;
    __syncthreads();            // covers redu (gi) and ghp (hh) writes; drains ax stores
    if (tid < 64) {
      const int hh_ = hb + tid;
      float r_ = 0.f, z_ = 0.f, in_ = 0.f, hn_ = 0.f;
#pragma unroll
      for (int w = 0; w < 8; ++w) {
        r_  += redu[w*256 +       tid] + ghp[w*192 +       tid];
        z_  += redu[w*256 +  64 + tid] + ghp[w*192 +  64 + tid];
        in_ += redu[w*256 + 128 + tid];
        hn_ += ghp[w*192 + 128 + tid];
      }
      float rg = 1.f/(1.f + __expf(-(r_ + p.bih[hh_] + p.bhh[hh_])));
      float zg = 1.f/(1.f + __expf(-(z_ + p.bih[512+hh_] + p.bhh[512+hh_])));
      float na = (in_ + p.bih[1024+hh_]) + rg*(hn_ + p.bhh[1024+hh_]);
      float e2 = __expf(2.f*na);
      float nn = 1.f - 2.f/(e2 + 1.f);
      float hnew = (1.f - zg)*nn + zg*hxL[hh_];
      // tagged publish: tag s+2, consumed at step s+1 (target (s+1)+1)
      gstll(p.hx64 + (size_t)b*HH + hh_, tagw((unsigned)(s+2), hnew));
    }
    // no trailing barrier: tags self-validate; LDS hazards covered by later barriers
  };

  gru_hh();
  gru_gi(-1);

  for (int s = 0; s < NSTEP; ++s) {
    // ---- gate A: per-element tagged spin on hx (+ ax window), single IC round trip ----
    {
      const unsigned tgtA = (unsigned)(s+1);
      const unsigned tga  = (unsigned)s;
      const ull* axb = p.axt + (size_t)b*AXP;
      int tg0 = -1, tg1 = -1;
      if (s > 0) {
        if (tid < 34) { tg0 = t0 - 8 + 2*tid; tg1 = t0 - 8 + 2*tid + 1; }
        else if (tid >= 64 && tid < 98) {
          int mm = tid - 64;
          tg0 = t0 - 8 + 2*mm + 1;
          tg1 = (2*mm + 2 < 68) ? (t0 - 8 + 2*mm + 2) : -1;
        }
        if (tg0 < 0 || tg0 >= TT) tg0 = -1;
        if (tg1 < 0 || tg1 >= TT) tg1 = -1;
      }
      ull vh = 0, va0 = 0, va1 = 0;
      unsigned it = 0;
      for (;;) {
        bool ok = true;
        vh = gldll(p.hx64 + (size_t)b*HH + tid);
        ok &= ((unsigned)(vh >> 32) == tgtA);
        if (tg0 >= 0) { va0 = gldll(axb + tg0); ok &= ((unsigned)(va0 >> 32) == tga); }
        if (tg1 >= 0) { va1 = gldll(axb + tg1); ok &= ((unsigned)(va1 >> 32) == tga); }
        if (ok) break;
        __builtin_amdgcn_s_sleep(1);
        if (++it > SPIN_CAP) break;
      }
      float hv = u2f((unsigned)vh);
      hxL[tid] = hv;
      hxh[tid] = (_Float16)hv;
      if (s > 0) {
        float a0 = (tg0 >= 0) ? u2f((unsigned)va0) : 0.f;
        float a1 = (tg1 >= 0) ? u2f((unsigned)va1) : 0.f;
        if (tid < 34) axp[tid] = v2h{(_Float16)a0, (_Float16)a1};
        else if (tid >= 64 && tid < 98) axp[34 + (tid-64)] = v2h{(_Float16)a0, (_Float16)a1};
      }
    }
    __syncthreads();
    // ---- score over own 50 t ----
    float hxr[8];
#pragma unroll
    for (int j = 0; j < 8; ++j) hxr[j] = hxL[h0s + j];
    float m = -1e30f, l = 0.f, acc[8];
#pragma unroll
    for (int j = 0; j < 8; ++j) acc[j] = 0.f;
#pragma unroll 2
    for (int lt = wave; lt < 50; lt += 8) {
      v8h xv = *(const v8h*)(xhL + lt*512 + h0s);
      float xr[8];
#pragma unroll
      for (int j = 0; j < 8; ++j) xr[j] = (float)xv[j];
      float cc[8];
      if (s > 0) {
        const int li0 = lt + 1;
        const v2h* ap2 = axp + ((li0 & 1) ? (34 + ((li0-1) >> 1)) : (li0 >> 1));
        v2h av2[8];
#pragma unroll
        for (int mm = 0; mm < 8; ++mm) av2[mm] = ap2[mm];
#pragma unroll
        for (int j = 0; j < 8; ++j) {
          float a = cbr[j];
#pragma unroll
          for (int mm = 0; mm < 8; ++mm) a = FDOT2(cwp[j][mm], av2[mm], a);
          cc[j] = a;
        }
      } else {
#pragma unroll
        for (int j = 0; j < 8; ++j) cc[j] = 0.f;
      }
      float part = 0.f;
#pragma unroll
      for (int j = 0; j < 8; ++j) {
        float vv = xr[j] + hxr[j] + cc[j];
        vv = fmaxf(vv, 0.f);
        part = fmaf(vv, awr[j], part);
      }
      part = wredsum(part);
      float st = part + atb;
      if (lane == 0) stL[lt] = st;
      float mn  = fmaxf(m, st);
      float scl = __expf(m - mn);
      float pe  = __expf(st - mn);
      l = l*scl + pe;
#pragma unroll
      for (int j = 0; j < 8; ++j) acc[j] = fmaf(acc[j], scl, pe*xr[j]);
      m = mn;
    }
    if (lane == 0) { mS[wave] = m; lS[wave] = l; }
    __syncthreads();
    float mb = mS[0];
#pragma unroll
    for (int w = 1; w < 8; ++w) mb = fmaxf(mb, mS[w]);
    float lb = 0.f;
#pragma unroll
    for (int w = 0; w < 8; ++w) lb = fmaf(__expf(mS[w] - mb), lS[w], lb);
    // ---- single-phase merge: each wave writes its scaled acc to its own 2KB stripe ----
    {
      const float sc = __expf(mS[wave] - mb);
      float* dst = redu + wave*512 + h0s;
#pragma unroll
      for (int j = 0; j < 8; ++j) dst[j] = sc*acc[j];
    }
    __syncthreads();
    float ab = 0.f;
#pragma unroll
    for (int w = 0; w < 8; ++w) ab += redu[w*512 + tid];
    // ---- tagged publish (no drain barrier: each word self-validates) ----
    gstll(&p.pacc64[((size_t)(b*8 + tch))*HH + tid], tagw((unsigned)(s+1), ab));
    if (tid == 0) {
      gstll(&p.pm64[b*8+tch], tagw((unsigned)(s+1), mb));
      gstll(&p.pl64[b*8+tch], tagw((unsigned)(s+1), lb));
    }
    float embr = 0.f;
    if (s < NSTEP-1)
      embr = p.emb[(size_t)p.y[b*LSEQ + (s+1)]*HH + tid];   // in flight during gate
    // ---- W_hh half of GRU in the gate-B shadow (hx(s) already in hxh) ----
    if (s < NSTEP-1) gru_hh();
    // ---- gate B: tagged spin directly on remote pacc + pm/pl, single IC round trip ----
    ull vv[8];
#pragma unroll
    for (int c = 0; c < 8; ++c) vv[c] = 0;
    {
      const unsigned tgtB = (unsigned)(s+1);
      ull vscal = 0;
      unsigned it = 0;
      for (;;) {
        bool ok = true;
#pragma unroll
        for (int c = 0; c < 8; ++c) if (c != tch) {
          vv[c] = gldll(&p.pacc64[((size_t)(b*8 + c))*HH + tid]);
          ok &= ((unsigned)(vv[c] >> 32) == tgtB);
        }
        if (tid < 8)       { vscal = gldll(&p.pm64[b*8 + tid]);     ok &= ((unsigned)(vscal >> 32) == tgtB); }
        else if (tid < 16) { vscal = gldll(&p.pl64[b*8 + tid - 8]); ok &= ((unsigned)(vscal >> 32) == tgtB); }
        if (ok) break;
        __builtin_amdgcn_s_sleep(1);
        if (++it > SPIN_CAP) break;
      }
      if (tid < 8)       pmL[tid]     = u2f((unsigned)vscal);
      else if (tid < 16) plL[tid - 8] = u2f((unsigned)vscal);
    }
    __syncthreads();
    float mm2 = pmL[0];
#pragma unroll
    for (int c = 1; c < 8; ++c) mm2 = fmaxf(mm2, pmL[c]);
    float ls = 0.f, ee[8];
#pragma unroll
    for (int c = 0; c < 8; ++c) { ee[c] = __expf(pmL[c] - mm2); ls = fmaf(ee[c], plL[c], ls); }
    float inv = 1.f / ls;
    float sv = 0.f;
#pragma unroll
    for (int c = 0; c < 8; ++c) {
      float pv = (c == tch) ? ab : u2f((unsigned)vv[c]);
      sv = fmaf(ee[c], pv, sv);
    }
    const float sxv = sv * inv;            // sx stays in a register
    if (tid < 50) {
      float a = __expf(stL[tid] - mm2) * inv;
      gstll(p.axt + (size_t)b*AXP + t0 + tid, tagw((unsigned)(s+1), a));
      p.out[AOFF + (size_t)b*NSTEP*TT + (size_t)s*TT + t0 + tid] = a;
    }
    if (s < NSTEP-1) ixh[tid] = (_Float16)(embr + sxv);
    __syncthreads();
    // ---- GRU gi half (critical path: 196KB stream; publishes tagged hx ASAP) ----
    if (s < NSTEP-1) gru_gi(s);
    // ---- FC (off critical path, in the hx shadow): Bh reuses ixh ----
    ixh[tid] = (_Float16)(hxL[tid] + sxv);
    __syncthreads();
    {
      const int rowg = hb + lane;
      const v2h* bp = (const v2h*)ixh;
      float pf = 0.f;
#pragma unroll 2
      for (int kb = 0; kb < 8; ++kb) {
        const int kbg = wave*8 + kb;
        const int pb  = kbg*4;
        v8h w = fwT[kbg*512 + rowg];
        DOT8(pf, w, bp[pb], bp[pb+1], bp[pb+2], bp[pb+3]);
      }
      redu[wave*64 + lane] = pf;
      __syncthreads();
      if (tid < 64) {
        float v = 0.f;
#pragma unroll
        for (int w = 0; w < 8; ++w) v += redu[w*64 + tid];
        const int r2 = hb + tid;
        if (r2 < VO)
          p.out[(size_t)b*NSTEP*VO + (size_t)s*VO + r2] = v + p.fb[r2];
      }
    }
  }
}

extern "C" void kernel_launch(void* const* d_in, const int* in_sizes, int n_in,
                              void* d_out, int out_size, void* d_ws, size_t ws_size,
                              hipStream_t stream) {
  P p;
  p.x   = (const float*)d_in[0];
  p.y   = (const int*)  d_in[1];
  p.emb = (const float*)d_in[2];
  p.wih = (const float*)d_in[3];
  p.whh = (const float*)d_in[4];
  p.bih = (const float*)d_in[5];
  p.bhh = (const float*)d_in[6];
  p.cw  = (const float*)d_in[7];
  p.cb  = (const float*)d_in[8];
  p.aw  = (const float*)d_in[9];
  p.ab  = (const float*)d_in[10];
  p.fw  = (const float*)d_in[11];
  p.fb  = (const float*)d_in[12];
  p.out = (float*)d_out;
  p.ctrl = (int*)d_ws;
  // layout: 48KB ctrl | tagged 1,290,240B (hx64|axt|pm64|pl64|pacc64) | fp16 weights 3.67MB
  char* base = (char*)d_ws;
  p.hx64   = (ull*)(base + 49152);                           // 131,072 B
  p.axt    = (ull*)(base + 49152 + 131072);                  // 106,496 B
  p.pm64   = (ull*)(base + 49152 + 131072 + 106496);         //   2,048 B
  p.pl64   = (ull*)(base + 49152 + 131072 + 106496 + 2048);  //   2,048 B
  p.pacc64 = (ull*)(base + 49152 + 131072 + 106496 + 4096);  // 1,048,576 B
  p.w16    = (_Float16*)(base + 49152 + 1290240);            // 3,670,016 B

  // zero ctrl + tagged region (stale tags from a previous launch alias exactly)
  hipMemsetAsync(d_ws, 0, 49152 + 1290240, stream);

  void* args[] = { &p };
  hipError_t err = hipLaunchCooperativeKernel((const void*)seq2seq_kernel,
                                              dim3(NBLK), dim3(NTHR), args, 0, stream);
  if (err != hipSuccess) {
    seq2seq_kernel<<<dim3(NBLK), dim3(NTHR), 0, stream>>>(p);
  }
}

// Round 8
// 1374.054 us; speedup vs baseline: 1.1145x; 1.1145x over previous
//
#include <hip/hip_runtime.h>

#define BB 32
#define TT 400
#define HH 512
#define NSTEP 100
#define VO 511
#define LSEQ 101
#define NBLK 256
#define NTHR 512
#define AOFF (BB*NSTEP*VO)
#define AXP 416
#define AG __HIP_MEMORY_SCOPE_AGENT
#define SPIN_CAP 20000000u

typedef float f4 __attribute__((ext_vector_type(4)));
typedef _Float16 v2h __attribute__((ext_vector_type(2)));
typedef _Float16 v8h __attribute__((ext_vector_type(8)));
typedef unsigned long long ull;

#if defined(__has_builtin)
#if __has_builtin(__builtin_amdgcn_fdot2)
#define HAVE_FDOT2 1
#endif
#endif
#ifdef HAVE_FDOT2
#define FDOT2(w, a, c) __builtin_amdgcn_fdot2((w), (a), (c), false)
#else
#define FDOT2(w, a, c) fmaf((float)(w)[0], (float)(a)[0], fmaf((float)(w)[1], (float)(a)[1], (c)))
#endif

// 8-k fdot2 block: weight v8h vs 4 activation pairs
#define DOT8(acc, wv, p0, p1, p2, p3)                      \
  acc = FDOT2((v2h{(wv)[0],(wv)[1]}), (p0), acc);          \
  acc = FDOT2((v2h{(wv)[2],(wv)[3]}), (p1), acc);          \
  acc = FDOT2((v2h{(wv)[4],(wv)[5]}), (p2), acc);          \
  acc = FDOT2((v2h{(wv)[6],(wv)[7]}), (p3), acc);

struct P {
  const float* x; const int* y; const float* emb;
  const float* wih; const float* whh; const float* bih; const float* bhh;
  const float* cw; const float* cb; const float* aw; const float* ab;
  const float* fw; const float* fb;
  float* out; int* ctrl;
  ull* hx64;            // tagged hx words [BB][HH]
  float* fws; _Float16* w16;
};

__device__ __forceinline__ float wredsum(float v) {
#pragma unroll
  for (int d = 1; d < 64; d <<= 1) v += __shfl_xor(v, d, 64);
  return v;
}
__device__ __forceinline__ unsigned f2u(float f){ union{float f;unsigned u;}c;c.f=f;return c.u; }
__device__ __forceinline__ float u2f(unsigned u){ union{unsigned u;float f;}c;c.u=u;return c.f; }
// uncached (IC coherence point) ops
__device__ __forceinline__ float gld(const float* q) {
  return __hip_atomic_load(q, __ATOMIC_RELAXED, AG);
}
__device__ __forceinline__ void gst(float* q, float v) {
  __hip_atomic_store(q, v, __ATOMIC_RELAXED, AG);
}
__device__ __forceinline__ unsigned gldi(const int* q) {
  return __hip_atomic_load((const unsigned*)q, __ATOMIC_RELAXED, AG);
}
__device__ __forceinline__ void gsti(int* q, unsigned v) {
  __hip_atomic_store((unsigned*)q, v, __ATOMIC_RELAXED, AG);
}
__device__ __forceinline__ ull gldll(const ull* q) {
  return __hip_atomic_load(q, __ATOMIC_RELAXED, AG);
}
__device__ __forceinline__ void gstll(ull* q, ull v) {
  __hip_atomic_store(q, v, __ATOMIC_RELAXED, AG);
}
__device__ __forceinline__ ull tagw(unsigned tag, float f) {
  return ((ull)tag << 32) | (ull)f2u(f);
}

__global__ __launch_bounds__(NTHR, 2) void seq2seq_kernel(P p) {
  const int tid  = threadIdx.x;
  const int lane = tid & 63;
  const int wave = tid >> 6;
  const int blk  = blockIdx.x;
  const int b   = blk >> 3;
  const int tch = blk & 7;
  const int t0  = tch * 50;
  const int hb  = tch * 64;
  const int h0s = lane * 8;

  // ---- LDS arena 78,736 B ----
  __shared__ __align__(16) char smem[78736];
  _Float16* xhL = (_Float16*)smem;                 // 51200: x chunk fp16
  float*    hxL = (float*)(smem + 51200);          // 2048: hx(s) fp32
  _Float16* ixh = (_Float16*)(smem + 53248);       // 1024: emb+sx fp16 (doubles as Bh for FC)
  _Float16* hxh = (_Float16*)(smem + 54272);       // 1024: hx fp16
  float*    redu= (float*)(smem + 55296);          // 16384: GRU-gi/FC partials ∪ score merge
  float*    axs = (float*)(smem + 71680);          // 272
  v2h*      axp = (v2h*)(smem + 71952);            // 280
  float*    stL = (float*)(smem + 72232);          // 224
  float*    mS  = (float*)(smem + 72456);          // 32
  float*    lS  = mS + 8; float* pmL = mS + 16; float* plL = mS + 24;
  float*    ghp = (float*)(smem + 72592);          // 6144: W_hh partials [8 waves][192]

  float* ax_rot = p.fws;                       // [2][BB][AXP]
  float* pm     = ax_rot + 2*BB*AXP;           // [BB*8]
  float* pl     = pm + 256;
  float* pacc   = pl + 256;                    // [BB][8][HH]
  const v8h* wiT = (const v8h*)p.w16;          // [3][64][512] ih (k-major)
  const v8h* whT = wiT + 98304;                // [3][64][512] hh
  const v8h* fwT = wiT + 196608;               // [64][512]    fc

  int* scf   = p.ctrl;               // score flags [(b*8+c)*16] = s+1
  int* initc = p.ctrl + 8192;
  int* scf_b = scf + b*128;

  auto wait8 = [&](int* base, unsigned target) {
    if (wave == 0) {
      unsigned it = 0;
      for (;;) {
        unsigned v = target;
        if (lane < 8) v = gldi(base + lane*16);
        if (__ballot(v < target) == 0ull) break;
        __builtin_amdgcn_s_sleep(1);
        if (++it > SPIN_CAP) break;
      }
    }
    __syncthreads();
  };

  // ---- persistent conv/attn weights ----
  v2h cwp[8][8]; float cbr[8], awr[8];
#pragma unroll
  for (int j = 0; j < 8; ++j) {
    int h = h0s + j;
    cbr[j] = p.cb[h]; awr[j] = p.aw[h];
#pragma unroll
    for (int mm = 0; mm < 8; ++mm) {
      float w0 = p.cw[h*15 + 2*mm];
      float w1 = (2*mm+1 < 15) ? p.cw[h*15 + 2*mm + 1] : 0.f;
      cwp[j][mm] = v2h{(_Float16)w0, (_Float16)w1};
    }
  }
  const float atb = p.ab[0];

  // ---- one-time: transposed fp16 weight build (k-major, h-contiguous) ----
  {
    const int gthr = NBLK*NTHR;
    const int gid = blk*NTHR + tid;
    auto cvt8 = [&](const float* s8, ull* dst) {
      v8h v;
#pragma unroll
      for (int e = 0; e < 8; ++e) v[e] = (_Float16)s8[e];
      union { v8h h; ull u[2]; } c; c.h = v;
      gstll(dst, c.u[0]); gstll(dst + 1, c.u[1]);
    };
    for (int i = gid; i < 98304; i += gthr) {
      int h = i & 511, kb = (i >> 9) & 63, g = i >> 15;
      cvt8(p.wih + ((size_t)(g*512 + h))*512 + kb*8, (ull*)((v8h*)p.w16 + i));
    }
    for (int i = gid; i < 98304; i += gthr) {
      int h = i & 511, kb = (i >> 9) & 63, g = i >> 15;
      cvt8(p.whh + ((size_t)(g*512 + h))*512 + kb*8, (ull*)((v8h*)p.w16 + 98304 + i));
    }
    for (int i = gid; i < 32768; i += gthr) {
      int h = i & 511, kb = i >> 9;
      ull* dst = (ull*)((v8h*)p.w16 + 196608 + i);
      if (h < VO) cvt8(p.fw + (size_t)h*512 + kb*8, dst);
      else { gstll(dst, 0ull); gstll(dst + 1, 0ull); }
    }
  }
  for (int i = 0; i < 50; ++i)
    xhL[i*512 + tid] = (_Float16)p.x[((size_t)b*TT + t0 + i)*HH + tid];
  hxL[tid] = 0.f;
  hxh[tid] = (_Float16)0.f;
  {
    const int yb = p.y[b*LSEQ + 0];
    ixh[tid] = (_Float16)p.emb[(size_t)yb*HH + tid];
  }
  __syncthreads();
  if (tid == 0) {
    __builtin_amdgcn_s_waitcnt(0);
    __hip_atomic_fetch_add((unsigned*)initc, 1u, __ATOMIC_RELAXED, AG);
    unsigned it = 0;
    while (__hip_atomic_load((unsigned*)initc, __ATOMIC_RELAXED, AG) < (unsigned)NBLK) {
      __builtin_amdgcn_s_sleep(2);
      if (++it > SPIN_CAP) break;
    }
  }
  __syncthreads();

  // ---- GRU split halves: gh = W_hh*hx (gate-B shadow), gi = W_ih*ix (critical) ----
  auto gru_hh = [&]() {
    const int hg = hb + lane;
    const v2h* hxp = (const v2h*)hxh;
    float pr = 0.f, pz = 0.f, phn = 0.f;
#pragma unroll 2
    for (int kb = 0; kb < 8; ++kb) {
      const int kbg = wave*8 + kb;
      const int pb  = kbg*4;
      v2h c0 = hxp[pb], c1 = hxp[pb+1], c2 = hxp[pb+2], c3 = hxp[pb+3];
      v8h wrh = whT[(0*64 + kbg)*512 + hg];
      v8h wzh = whT[(1*64 + kbg)*512 + hg];
      v8h wnh = whT[(2*64 + kbg)*512 + hg];
      DOT8(pr,  wrh, c0, c1, c2, c3);
      DOT8(pz,  wzh, c0, c1, c2, c3);
      DOT8(phn, wnh, c0, c1, c2, c3);
    }
    ghp[wave*192 +   0 + lane] = pr;
    ghp[wave*192 +  64 + lane] = pz;
    ghp[wave*192 + 128 + lane] = phn;
    // no barrier: consumed after gru_gi's internal barrier
  };

  auto gru_gi = [&](int s) {
    const int hg = hb + lane;
    const v2h* ixp = (const v2h*)ixh;
    float pr = 0.f, pz = 0.f, pin = 0.f;
#pragma unroll 2
    for (int kb = 0; kb < 8; ++kb) {
      const int kbg = wave*8 + kb;
      const int pb  = kbg*4;
      v2h a0 = ixp[pb], a1 = ixp[pb+1], a2 = ixp[pb+2], a3 = ixp[pb+3];
      v8h wri = wiT[(0*64 + kbg)*512 + hg];
      v8h wzi = wiT[(1*64 + kbg)*512 + hg];
      v8h wni = wiT[(2*64 + kbg)*512 + hg];
      DOT8(pr,  wri, a0, a1, a2, a3);
      DOT8(pz,  wzi, a0, a1, a2, a3);
      DOT8(pin, wni, a0, a1, a2, a3);
    }
    redu[wave*256 +   0 + lane] = pr;
    redu[wave*256 +  64 + lane] = pz;
    redu[wave*256 + 128 + lane] = pin;
    __syncthreads();            // covers redu (gi) + ghp (hh) writes; drains ax stores (vmcnt0)
    if (tid < 64) {
      const int hh_ = hb + tid;
      float r_ = 0.f, z_ = 0.f, in_ = 0.f, hn_ = 0.f;
#pragma unroll
      for (int w = 0; w < 8; ++w) {
        r_  += redu[w*256 +       tid] + ghp[w*192 +       tid];
        z_  += redu[w*256 +  64 + tid] + ghp[w*192 +  64 + tid];
        in_ += redu[w*256 + 128 + tid];
        hn_ += ghp[w*192 + 128 + tid];
      }
      float rg = 1.f/(1.f + __expf(-(r_ + p.bih[hh_] + p.bhh[hh_])));
      float zg = 1.f/(1.f + __expf(-(z_ + p.bih[512+hh_] + p.bhh[512+hh_])));
      float na = (in_ + p.bih[1024+hh_]) + rg*(hn_ + p.bhh[1024+hh_]);
      float e2 = __expf(2.f*na);
      float nn = 1.f - 2.f/(e2 + 1.f);
      float hnew = (1.f - zg)*nn + zg*hxL[hh_];
      // tagged publish: tag s+2, consumed at step s+1 (target (s+1)+1)
      gstll(p.hx64 + (size_t)b*HH + hh_, tagw((unsigned)(s+2), hnew));
    }
    // no trailing barrier / no flag: tags self-validate; LDS hazards covered by later barriers
  };

  gru_hh();
  gru_gi(-1);

  for (int s = 0; s < NSTEP; ++s) {
    const int par = s & 1;
    // ---- gate A: spin directly on own tagged hx word (one IC round trip) ----
    {
      const unsigned tgtA = (unsigned)(s+1);
      ull vh;
      unsigned it = 0;
      for (;;) {
        vh = gldll(p.hx64 + (size_t)b*HH + tid);
        if ((unsigned)(vh >> 32) == tgtA) break;
        __builtin_amdgcn_s_sleep(1);
        if (++it > SPIN_CAP) break;
      }
      float hv = u2f((unsigned)vh);
      // ax(s-1) visible: producer's hx-tag store is after the gi barrier that drained ax stores
      if (s > 0 && tid < 68) {
        int tg = t0 - 8 + tid;
        axs[tid] = (tg >= 0 && tg < TT)
                 ? gld(ax_rot + (size_t)((s-1)&1)*BB*AXP + (size_t)b*AXP + tg) : 0.f;
      }
      hxL[tid] = hv;
      hxh[tid] = (_Float16)hv;
    }
    __syncthreads();
    if (s > 0) {
      if (tid < 34) axp[tid] = v2h{(_Float16)axs[2*tid], (_Float16)axs[2*tid+1]};
      else if (tid >= 64 && tid < 98) {
        int mm = tid - 64;
        float a1 = (2*mm+2 < 68) ? axs[2*mm+2] : 0.f;
        axp[34+mm] = v2h{(_Float16)axs[2*mm+1], (_Float16)a1};
      }
      __syncthreads();
    }
    // ---- score over own 50 t ----
    float hxr[8];
#pragma unroll
    for (int j = 0; j < 8; ++j) hxr[j] = hxL[h0s + j];
    float m = -1e30f, l = 0.f, acc[8];
#pragma unroll
    for (int j = 0; j < 8; ++j) acc[j] = 0.f;
#pragma unroll 2
    for (int lt = wave; lt < 50; lt += 8) {
      v8h xv = *(const v8h*)(xhL + lt*512 + h0s);
      float xr[8];
#pragma unroll
      for (int j = 0; j < 8; ++j) xr[j] = (float)xv[j];
      float cc[8];
      if (s > 0) {
        const int li0 = lt + 1;
        const v2h* ap2 = axp + ((li0 & 1) ? (34 + ((li0-1) >> 1)) : (li0 >> 1));
        v2h av2[8];
#pragma unroll
        for (int mm = 0; mm < 8; ++mm) av2[mm] = ap2[mm];
#pragma unroll
        for (int j = 0; j < 8; ++j) {
          float a = cbr[j];
#pragma unroll
          for (int mm = 0; mm < 8; ++mm) a = FDOT2(cwp[j][mm], av2[mm], a);
          cc[j] = a;
        }
      } else {
#pragma unroll
        for (int j = 0; j < 8; ++j) cc[j] = 0.f;
      }
      float part = 0.f;
#pragma unroll
      for (int j = 0; j < 8; ++j) {
        float vv = xr[j] + hxr[j] + cc[j];
        vv = fmaxf(vv, 0.f);
        part = fmaf(vv, awr[j], part);
      }
      part = wredsum(part);
      float st = part + atb;
      if (lane == 0) stL[lt] = st;
      float mn  = fmaxf(m, st);
      float scl = __expf(m - mn);
      float pe  = __expf(st - mn);
      l = l*scl + pe;
#pragma unroll
      for (int j = 0; j < 8; ++j) acc[j] = fmaf(acc[j], scl, pe*xr[j]);
      m = mn;
    }
    if (lane == 0) { mS[wave] = m; lS[wave] = l; }
    __syncthreads();
    float mb = mS[0];
#pragma unroll
    for (int w = 1; w < 8; ++w) mb = fmaxf(mb, mS[w]);
    float lb = 0.f;
#pragma unroll
    for (int w = 0; w < 8; ++w) lb = fmaf(__expf(mS[w] - mb), lS[w], lb);
    // ---- single-phase merge: each wave writes its scaled acc to its own 2KB stripe ----
    {
      const float sc = __expf(mS[wave] - mb);
      float* dst = redu + wave*512 + h0s;
#pragma unroll
      for (int j = 0; j < 8; ++j) dst[j] = sc*acc[j];
    }
    __syncthreads();
    float ab = 0.f;
#pragma unroll
    for (int w = 0; w < 8; ++w) ab += redu[w*512 + tid];
    gst(&pacc[(size_t)(b*8 + tch)*HH + tid], ab);
    if (tid == 0) { gst(&pm[b*8+tch], mb); gst(&pl[b*8+tch], lb); }
    __syncthreads();                       // all waves drain partial stores
    if (tid == 0) gsti(scf_b + tch*16, (unsigned)(s+1));
    float embr = 0.f;
    if (s < NSTEP-1)
      embr = p.emb[(size_t)p.y[b*LSEQ + (s+1)]*HH + tid];   // in flight during gate
    // ---- W_hh half of GRU in the gate-B shadow (hx(s) already in hxh) ----
    if (s < NSTEP-1) gru_hh();
    wait8(scf_b, (unsigned)(s+1));
    // ---- combine (redundant per team block) ----
    if (tid < 8)       pmL[tid]   = gld(&pm[b*8 + tid]);
    else if (tid < 16) plL[tid-8] = gld(&pl[b*8 + tid - 8]);
    __syncthreads();
    float mm2 = pmL[0];
#pragma unroll
    for (int c = 1; c < 8; ++c) mm2 = fmaxf(mm2, pmL[c]);
    float ls = 0.f, ee[8];
#pragma unroll
    for (int c = 0; c < 8; ++c) { ee[c] = __expf(pmL[c] - mm2); ls = fmaf(ee[c], plL[c], ls); }
    float inv = 1.f / ls;
    float sv = 0.f;
#pragma unroll
    for (int c = 0; c < 8; ++c) {
      float pv = (c == tch) ? ab : gld(&pacc[(size_t)(b*8+c)*HH + tid]);
      sv = fmaf(ee[c], pv, sv);
    }
    const float sxv = sv * inv;            // sx stays in a register
    if (tid < 50) {
      float a = __expf(stL[tid] - mm2) * inv;
      gst(ax_rot + (size_t)par*BB*AXP + (size_t)b*AXP + t0 + tid, a);
      p.out[AOFF + (size_t)b*NSTEP*TT + (size_t)s*TT + t0 + tid] = a;
    }
    if (s < NSTEP-1) ixh[tid] = (_Float16)(embr + sxv);
    __syncthreads();
    // ---- GRU gi half (critical path; publishes tagged hx ASAP, no flag trip) ----
    if (s < NSTEP-1) gru_gi(s);
    // ---- FC (off critical path): Bh reuses ixh ----
    ixh[tid] = (_Float16)(hxL[tid] + sxv);
    __syncthreads();
    {
      const int rowg = hb + lane;
      const v2h* bp = (const v2h*)ixh;
      float pf = 0.f;
#pragma unroll 2
      for (int kb = 0; kb < 8; ++kb) {
        const int kbg = wave*8 + kb;
        const int pb  = kbg*4;
        v8h w = fwT[kbg*512 + rowg];
        DOT8(pf, w, bp[pb], bp[pb+1], bp[pb+2], bp[pb+3]);
      }
      redu[wave*64 + lane] = pf;
      __syncthreads();
      if (tid < 64) {
        float v = 0.f;
#pragma unroll
        for (int w = 0; w < 8; ++w) v += redu[w*64 + tid];
        const int r2 = hb + tid;
        if (r2 < VO)
          p.out[(size_t)b*NSTEP*VO + (size_t)s*VO + r2] = v + p.fb[r2];
      }
    }
  }
}

extern "C" void kernel_launch(void* const* d_in, const int* in_sizes, int n_in,
                              void* d_out, int out_size, void* d_ws, size_t ws_size,
                              hipStream_t stream) {
  P p;
  p.x   = (const float*)d_in[0];
  p.y   = (const int*)  d_in[1];
  p.emb = (const float*)d_in[2];
  p.wih = (const float*)d_in[3];
  p.whh = (const float*)d_in[4];
  p.bih = (const float*)d_in[5];
  p.bhh = (const float*)d_in[6];
  p.cw  = (const float*)d_in[7];
  p.cb  = (const float*)d_in[8];
  p.aw  = (const float*)d_in[9];
  p.ab  = (const float*)d_in[10];
  p.fw  = (const float*)d_in[11];
  p.fb  = (const float*)d_in[12];
  p.out = (float*)d_out;
  p.ctrl = (int*)d_ws;
  // layout: 48KB ctrl | hx64 tagged 131,072B | fws floats | fp16 weights 3.67MB
  char* base = (char*)d_ws;
  p.hx64 = (ull*)(base + 49152);
  size_t flcount = (size_t)2*BB*AXP + 512 + (size_t)BB*8*HH;
  p.fws = (float*)(base + 49152 + 131072);
  p.w16 = (_Float16*)(base + 49152 + 131072 + 4*flcount);

  // zero ctrl + hx64 (stale tags from a previous launch alias exactly)
  hipMemsetAsync(d_ws, 0, 49152 + 131072, stream);

  void* args[] = { &p };
  hipError_t err = hipLaunchCooperativeKernel((const void*)seq2seq_kernel,
                                              dim3(NBLK), dim3(NTHR), args, 0, stream);
  if (err != hipSuccess) {
    seq2seq_kernel<<<dim3(NBLK), dim3(NTHR), 0, stream>>>(p);
  }
}

// Round 10
// 1304.136 us; speedup vs baseline: 1.1742x; 1.0536x over previous
//
#include <hip/hip_runtime.h>

#define BB 32
#define TT 400
#define HH 512
#define NSTEP 100
#define VO 511
#define LSEQ 101
#define NBLK 256
#define NTHR 512
#define AOFF (BB*NSTEP*VO)
#define AXP 416
#define AG __HIP_MEMORY_SCOPE_AGENT
#define SPIN_CAP 20000000u
#define KBL 24   // kbg groups of W_ih cached in LDS (waves 0-2)

typedef float f4 __attribute__((ext_vector_type(4)));
typedef _Float16 v2h __attribute__((ext_vector_type(2)));
typedef _Float16 v8h __attribute__((ext_vector_type(8)));
typedef unsigned long long ull;

#if defined(__has_builtin)
#if __has_builtin(__builtin_amdgcn_fdot2)
#define HAVE_FDOT2 1
#endif
#endif
#ifdef HAVE_FDOT2
#define FDOT2(w, a, c) __builtin_amdgcn_fdot2((w), (a), (c), false)
#else
#define FDOT2(w, a, c) fmaf((float)(w)[0], (float)(a)[0], fmaf((float)(w)[1], (float)(a)[1], (c)))
#endif

// 8-k fdot2 block: weight v8h vs 4 activation pairs
#define DOT8(acc, wv, p0, p1, p2, p3)                      \
  acc = FDOT2((v2h{(wv)[0],(wv)[1]}), (p0), acc);          \
  acc = FDOT2((v2h{(wv)[2],(wv)[3]}), (p1), acc);          \
  acc = FDOT2((v2h{(wv)[4],(wv)[5]}), (p2), acc);          \
  acc = FDOT2((v2h{(wv)[6],(wv)[7]}), (p3), acc);

struct P {
  const float* x; const int* y; const float* emb;
  const float* wih; const float* whh; const float* bih; const float* bhh;
  const float* cw; const float* cb; const float* aw; const float* ab;
  const float* fw; const float* fb;
  float* out; int* ctrl;
  ull* hx64;            // tagged hx words [BB][HH]
  float* fws; _Float16* w16;
};

__device__ __forceinline__ float wredsum(float v) {
#pragma unroll
  for (int d = 1; d < 64; d <<= 1) v += __shfl_xor(v, d, 64);
  return v;
}
__device__ __forceinline__ unsigned f2u(float f){ union{float f;unsigned u;}c;c.f=f;return c.u; }
__device__ __forceinline__ float u2f(unsigned u){ union{unsigned u;float f;}c;c.u=u;return c.f; }
// uncached (IC coherence point) ops
__device__ __forceinline__ float gld(const float* q) {
  return __hip_atomic_load(q, __ATOMIC_RELAXED, AG);
}
__device__ __forceinline__ void gst(float* q, float v) {
  __hip_atomic_store(q, v, __ATOMIC_RELAXED, AG);
}
__device__ __forceinline__ unsigned gldi(const int* q) {
  return __hip_atomic_load((const unsigned*)q, __ATOMIC_RELAXED, AG);
}
__device__ __forceinline__ void gsti(int* q, unsigned v) {
  __hip_atomic_store((unsigned*)q, v, __ATOMIC_RELAXED, AG);
}
__device__ __forceinline__ ull gldll(const ull* q) {
  return __hip_atomic_load(q, __ATOMIC_RELAXED, AG);
}
__device__ __forceinline__ void gstll(ull* q, ull v) {
  __hip_atomic_store(q, v, __ATOMIC_RELAXED, AG);
}
__device__ __forceinline__ ull tagw(unsigned tag, float f) {
  return ((ull)tag << 32) | (ull)f2u(f);
}

__global__ __launch_bounds__(NTHR, 2) void seq2seq_kernel(P p) {
  const int tid  = threadIdx.x;
  const int lane = tid & 63;
  const int wave = tid >> 6;
  const int blk  = blockIdx.x;
  const int b   = blk >> 3;
  const int tch = blk & 7;
  const int t0  = tch * 50;
  const int hb  = tch * 64;
  const int h0s = lane * 8;

  // ---- LDS arena 78,736 B + 73,728 B W_ih cache = 152,464 B ----
  __shared__ __align__(16) char smem[152464];
  _Float16* xhL = (_Float16*)smem;                 // 51200: x chunk fp16
  float*    hxL = (float*)(smem + 51200);          // 2048: hx(s) fp32
  _Float16* ixh = (_Float16*)(smem + 53248);       // 1024: emb+sx fp16 (doubles as Bh for FC)
  _Float16* hxh = (_Float16*)(smem + 54272);       // 1024: hx fp16
  float*    redu= (float*)(smem + 55296);          // 16384: GRU-gi/FC partials ∪ score merge
  float*    axs = (float*)(smem + 71680);          // 272
  v2h*      axp = (v2h*)(smem + 71952);            // 280
  float*    stL = (float*)(smem + 72232);          // 224
  float*    mS  = (float*)(smem + 72456);          // 32
  float*    lS  = mS + 8; float* pmL = mS + 16; float* plL = mS + 24;
  float*    ghp = (float*)(smem + 72592);          // 6144: W_hh partials [8 waves][192]
  v8h*      wihL= (v8h*)(smem + 78736);            // 73728: W_ih LDS cache [3][KBL][64] v8h

  float* ax_rot = p.fws;                       // [2][BB][AXP]
  float* pm     = ax_rot + 2*BB*AXP;           // [BB*8]
  float* pl     = pm + 256;
  float* pacc   = pl + 256;                    // [BB][8][HH]
  const v8h* wiT = (const v8h*)p.w16;          // [3][64][512] ih (k-major)
  const v8h* whT = wiT + 98304;                // [3][64][512] hh
  const v8h* fwT = wiT + 196608;               // [64][512]    fc

  int* scf   = p.ctrl;               // score flags [(b*8+c)*16] = s+1
  int* initc = p.ctrl + 8192;
  int* scf_b = scf + b*128;

  auto wait8 = [&](int* base, unsigned target) {
    if (wave == 0) {
      unsigned it = 0;
      for (;;) {
        unsigned v = target;
        if (lane < 8) v = gldi(base + lane*16);
        if (__ballot(v < target) == 0ull) break;
        __builtin_amdgcn_s_sleep(1);
        if (++it > SPIN_CAP) break;
      }
    }
    __syncthreads();
  };

  // ---- persistent conv/attn weights ----
  v2h cwp[8][8]; float cbr[8], awr[8];
#pragma unroll
  for (int j = 0; j < 8; ++j) {
    int h = h0s + j;
    cbr[j] = p.cb[h]; awr[j] = p.aw[h];
#pragma unroll
    for (int mm = 0; mm < 8; ++mm) {
      float w0 = p.cw[h*15 + 2*mm];
      float w1 = (2*mm+1 < 15) ? p.cw[h*15 + 2*mm + 1] : 0.f;
      cwp[j][mm] = v2h{(_Float16)w0, (_Float16)w1};
    }
  }
  const float atb = p.ab[0];

  // ---- one-time: transposed fp16 weight build (k-major, h-contiguous) ----
  {
    const int gthr = NBLK*NTHR;
    const int gid = blk*NTHR + tid;
    auto cvt8 = [&](const float* s8, ull* dst) {
      v8h v;
#pragma unroll
      for (int e = 0; e < 8; ++e) v[e] = (_Float16)s8[e];
      union { v8h h; ull u[2]; } c; c.h = v;
      gstll(dst, c.u[0]); gstll(dst + 1, c.u[1]);
    };
    for (int i = gid; i < 98304; i += gthr) {
      int h = i & 511, kb = (i >> 9) & 63, g = i >> 15;
      cvt8(p.wih + ((size_t)(g*512 + h))*512 + kb*8, (ull*)((v8h*)p.w16 + i));
    }
    for (int i = gid; i < 98304; i += gthr) {
      int h = i & 511, kb = (i >> 9) & 63, g = i >> 15;
      cvt8(p.whh + ((size_t)(g*512 + h))*512 + kb*8, (ull*)((v8h*)p.w16 + 98304 + i));
    }
    for (int i = gid; i < 32768; i += gthr) {
      int h = i & 511, kb = i >> 9;
      ull* dst = (ull*)((v8h*)p.w16 + 196608 + i);
      if (h < VO) cvt8(p.fw + (size_t)h*512 + kb*8, dst);
      else { gstll(dst, 0ull); gstll(dst + 1, 0ull); }
    }
  }
  for (int i = 0; i < 50; ++i)
    xhL[i*512 + tid] = (_Float16)p.x[((size_t)b*TT + t0 + i)*HH + tid];
  hxL[tid] = 0.f;
  hxh[tid] = (_Float16)0.f;
  {
    const int yb = p.y[b*LSEQ + 0];
    ixh[tid] = (_Float16)p.emb[(size_t)yb*HH + tid];
  }
  __syncthreads();
  if (tid == 0) {
    __builtin_amdgcn_s_waitcnt(0);
    __hip_atomic_fetch_add((unsigned*)initc, 1u, __ATOMIC_RELAXED, AG);
    unsigned it = 0;
    while (__hip_atomic_load((unsigned*)initc, __ATOMIC_RELAXED, AG) < (unsigned)NBLK) {
      __builtin_amdgcn_s_sleep(2);
      if (++it > SPIN_CAP) break;
    }
  }
  __syncthreads();
  // ---- one-time: W_ih k-groups 0..KBL-1 into LDS (read by waves 0-2 in gi) ----
  for (int i = tid; i < 3*KBL*64; i += NTHR) {
    int l = i & 63, t = i >> 6, kbg = t % KBL, g = t / KBL;
    wihL[(g*KBL + kbg)*64 + l] = wiT[((size_t)(g*64 + kbg))*512 + hb + l];
  }
  __syncthreads();

  // ---- GRU split halves: gh = W_hh*hx (gate-B shadow), gi = W_ih*ix (critical) ----
  auto gru_hh = [&]() {
    const int hg = hb + lane;
    const v2h* hxp = (const v2h*)hxh;
    float pr = 0.f, pz = 0.f, phn = 0.f;
#pragma unroll 2
    for (int kb = 0; kb < 8; ++kb) {
      const int kbg = wave*8 + kb;
      const int pb  = kbg*4;
      v2h c0 = hxp[pb], c1 = hxp[pb+1], c2 = hxp[pb+2], c3 = hxp[pb+3];
      v8h wrh = whT[(0*64 + kbg)*512 + hg];
      v8h wzh = whT[(1*64 + kbg)*512 + hg];
      v8h wnh = whT[(2*64 + kbg)*512 + hg];
      DOT8(pr,  wrh, c0, c1, c2, c3);
      DOT8(pz,  wzh, c0, c1, c2, c3);
      DOT8(phn, wnh, c0, c1, c2, c3);
    }
    ghp[wave*192 +   0 + lane] = pr;
    ghp[wave*192 +  64 + lane] = pz;
    ghp[wave*192 + 128 + lane] = phn;
    // no barrier: consumed after gru_gi's internal barrier
  };

  auto gru_gi = [&](int s) {
    const int hg = hb + lane;
    const v2h* ixp = (const v2h*)ixh;
    float pr = 0.f, pz = 0.f, pin = 0.f;
    if (wave < 3) {
      // W_ih from LDS cache (kbg = wave*8+kb < 24)
#pragma unroll 2
      for (int kb = 0; kb < 8; ++kb) {
        const int kbg = wave*8 + kb;
        const int pb  = kbg*4;
        v2h a0 = ixp[pb], a1 = ixp[pb+1], a2 = ixp[pb+2], a3 = ixp[pb+3];
        v8h wri = wihL[(0*KBL + kbg)*64 + lane];
        v8h wzi = wihL[(1*KBL + kbg)*64 + lane];
        v8h wni = wihL[(2*KBL + kbg)*64 + lane];
        DOT8(pr,  wri, a0, a1, a2, a3);
        DOT8(pz,  wzi, a0, a1, a2, a3);
        DOT8(pin, wni, a0, a1, a2, a3);
      }
    } else {
#pragma unroll 2
      for (int kb = 0; kb < 8; ++kb) {
        const int kbg = wave*8 + kb;
        const int pb  = kbg*4;
        v2h a0 = ixp[pb], a1 = ixp[pb+1], a2 = ixp[pb+2], a3 = ixp[pb+3];
        v8h wri = wiT[(0*64 + kbg)*512 + hg];
        v8h wzi = wiT[(1*64 + kbg)*512 + hg];
        v8h wni = wiT[(2*64 + kbg)*512 + hg];
        DOT8(pr,  wri, a0, a1, a2, a3);
        DOT8(pz,  wzi, a0, a1, a2, a3);
        DOT8(pin, wni, a0, a1, a2, a3);
      }
    }
    redu[wave*256 +   0 + lane] = pr;
    redu[wave*256 +  64 + lane] = pz;
    redu[wave*256 + 128 + lane] = pin;
    __syncthreads();            // covers redu (gi) + ghp (hh) writes; drains ax stores (vmcnt0)
    if (tid < 64) {
      const int hh_ = hb + tid;
      float r_ = 0.f, z_ = 0.f, in_ = 0.f, hn_ = 0.f;
#pragma unroll
      for (int w = 0; w < 8; ++w) {
        r_  += redu[w*256 +       tid] + ghp[w*192 +       tid];
        z_  += redu[w*256 +  64 + tid] + ghp[w*192 +  64 + tid];
        in_ += redu[w*256 + 128 + tid];
        hn_ += ghp[w*192 + 128 + tid];
      }
      float rg = 1.f/(1.f + __expf(-(r_ + p.bih[hh_] + p.bhh[hh_])));
      float zg = 1.f/(1.f + __expf(-(z_ + p.bih[512+hh_] + p.bhh[512+hh_])));
      float na = (in_ + p.bih[1024+hh_]) + rg*(hn_ + p.bhh[1024+hh_]);
      float e2 = __expf(2.f*na);
      float nn = 1.f - 2.f/(e2 + 1.f);
      float hnew = (1.f - zg)*nn + zg*hxL[hh_];
      // tagged publish: tag s+2, consumed at step s+1 (target (s+1)+1)
      gstll(p.hx64 + (size_t)b*HH + hh_, tagw((unsigned)(s+2), hnew));
    }
    // no trailing barrier / no flag: tags self-validate; LDS hazards covered by later barriers
  };

  gru_hh();
  gru_gi(-1);

  for (int s = 0; s < NSTEP; ++s) {
    const int par = s & 1;
    // ---- gate A: spin directly on own tagged hx word (one IC round trip) ----
    {
      const unsigned tgtA = (unsigned)(s+1);
      ull vh;
      unsigned it = 0;
      for (;;) {
        vh = gldll(p.hx64 + (size_t)b*HH + tid);
        if ((unsigned)(vh >> 32) == tgtA) break;
        __builtin_amdgcn_s_sleep(1);
        if (++it > SPIN_CAP) break;
      }
      float hv = u2f((unsigned)vh);
      // ax(s-1) visible: producer's hx-tag store is after the gi barrier that drained ax stores
      if (s > 0 && tid < 68) {
        int tg = t0 - 8 + tid;
        axs[tid] = (tg >= 0 && tg < TT)
                 ? gld(ax_rot + (size_t)((s-1)&1)*BB*AXP + (size_t)b*AXP + tg) : 0.f;
      }
      hxL[tid] = hv;
      hxh[tid] = (_Float16)hv;
    }
    __syncthreads();
    if (s > 0) {
      if (tid < 34) axp[tid] = v2h{(_Float16)axs[2*tid], (_Float16)axs[2*tid+1]};
      else if (tid >= 64 && tid < 98) {
        int mm = tid - 64;
        float a1 = (2*mm+2 < 68) ? axs[2*mm+2] : 0.f;
        axp[34+mm] = v2h{(_Float16)axs[2*mm+1], (_Float16)a1};
      }
      __syncthreads();
    }
    // ---- score over own 50 t ----
    float hxr[8];
#pragma unroll
    for (int j = 0; j < 8; ++j) hxr[j] = hxL[h0s + j];
    float m = -1e30f, l = 0.f, acc[8];
#pragma unroll
    for (int j = 0; j < 8; ++j) acc[j] = 0.f;
#pragma unroll 2
    for (int lt = wave; lt < 50; lt += 8) {
      v8h xv = *(const v8h*)(xhL + lt*512 + h0s);
      float xr[8];
#pragma unroll
      for (int j = 0; j < 8; ++j) xr[j] = (float)xv[j];
      float cc[8];
      if (s > 0) {
        const int li0 = lt + 1;
        const v2h* ap2 = axp + ((li0 & 1) ? (34 + ((li0-1) >> 1)) : (li0 >> 1));
        v2h av2[8];
#pragma unroll
        for (int mm = 0; mm < 8; ++mm) av2[mm] = ap2[mm];
#pragma unroll
        for (int j = 0; j < 8; ++j) {
          float a = cbr[j];
#pragma unroll
          for (int mm = 0; mm < 8; ++mm) a = FDOT2(cwp[j][mm], av2[mm], a);
          cc[j] = a;
        }
      } else {
#pragma unroll
        for (int j = 0; j < 8; ++j) cc[j] = 0.f;
      }
      float part = 0.f;
#pragma unroll
      for (int j = 0; j < 8; ++j) {
        float vv = xr[j] + hxr[j] + cc[j];
        vv = fmaxf(vv, 0.f);
        part = fmaf(vv, awr[j], part);
      }
      part = wredsum(part);
      float st = part + atb;
      if (lane == 0) stL[lt] = st;
      float mn  = fmaxf(m, st);
      float scl = __expf(m - mn);
      float pe  = __expf(st - mn);
      l = l*scl + pe;
#pragma unroll
      for (int j = 0; j < 8; ++j) acc[j] = fmaf(acc[j], scl, pe*xr[j]);
      m = mn;
    }
    // ---- single-barrier merge: unscaled stripes + per-wave m/l, consumer-side scaling ----
    if (lane == 0) { mS[wave] = m; lS[wave] = l; }
    {
      float* dst = redu + wave*512 + h0s;
#pragma unroll
      for (int j = 0; j < 8; ++j) dst[j] = acc[j];
    }
    __syncthreads();
    float mb = mS[0];
#pragma unroll
    for (int w = 1; w < 8; ++w) mb = fmaxf(mb, mS[w]);
    float lb = 0.f, ew[8];
#pragma unroll
    for (int w = 0; w < 8; ++w) { ew[w] = __expf(mS[w] - mb); lb = fmaf(ew[w], lS[w], lb); }
    float ab = 0.f;
#pragma unroll
    for (int w = 0; w < 8; ++w) ab = fmaf(ew[w], redu[w*512 + tid], ab);
    gst(&pacc[(size_t)(b*8 + tch)*HH + tid], ab);
    if (tid == 0) { gst(&pm[b*8+tch], mb); gst(&pl[b*8+tch], lb); }
    __syncthreads();                       // all waves drain partial stores
    if (tid == 0) gsti(scf_b + tch*16, (unsigned)(s+1));
    float embr = 0.f;
    if (s < NSTEP-1)
      embr = p.emb[(size_t)p.y[b*LSEQ + (s+1)]*HH + tid];   // in flight during gate
    // ---- W_hh half of GRU in the gate-B shadow (hx(s) already in hxh) ----
    if (s < NSTEP-1) gru_hh();
    wait8(scf_b, (unsigned)(s+1));
    // ---- combine (redundant per team block) ----
    if (tid < 8)       pmL[tid]   = gld(&pm[b*8 + tid]);
    else if (tid < 16) plL[tid-8] = gld(&pl[b*8 + tid - 8]);
    __syncthreads();
    float mm2 = pmL[0];
#pragma unroll
    for (int c = 1; c < 8; ++c) mm2 = fmaxf(mm2, pmL[c]);
    float ls = 0.f, ee[8];
#pragma unroll
    for (int c = 0; c < 8; ++c) { ee[c] = __expf(pmL[c] - mm2); ls = fmaf(ee[c], plL[c], ls); }
    float inv = 1.f / ls;
    float sv = 0.f;
#pragma unroll
    for (int c = 0; c < 8; ++c) {
      float pv = (c == tch) ? ab : gld(&pacc[(size_t)(b*8+c)*HH + tid]);
      sv = fmaf(ee[c], pv, sv);
    }
    const float sxv = sv * inv;            // sx stays in a register
    if (tid < 50) {
      float a = __expf(stL[tid] - mm2) * inv;
      gst(ax_rot + (size_t)par*BB*AXP + (size_t)b*AXP + t0 + tid, a);
      p.out[AOFF + (size_t)b*NSTEP*TT + (size_t)s*TT + t0 + tid] = a;
    }
    if (s < NSTEP-1) ixh[tid] = (_Float16)(embr + sxv);
    __syncthreads();
    // ---- GRU gi half (critical path; 3/8 of W_ih from LDS, publishes tagged hx ASAP) ----
    if (s < NSTEP-1) gru_gi(s);
    // ---- FC (off critical path): Bh reuses ixh ----
    ixh[tid] = (_Float16)(hxL[tid] + sxv);
    __syncthreads();
    {
      const int rowg = hb + lane;
      const v2h* bp = (const v2h*)ixh;
      float pf = 0.f;
#pragma unroll 2
      for (int kb = 0; kb < 8; ++kb) {
        const int kbg = wave*8 + kb;
        const int pb  = kbg*4;
        v8h w = fwT[kbg*512 + rowg];
        DOT8(pf, w, bp[pb], bp[pb+1], bp[pb+2], bp[pb+3]);
      }
      redu[wave*64 + lane] = pf;
      __syncthreads();
      if (tid < 64) {
        float v = 0.f;
#pragma unroll
        for (int w = 0; w < 8; ++w) v += redu[w*64 + tid];
        const int r2 = hb + tid;
        if (r2 < VO)
          p.out[(size_t)b*NSTEP*VO + (size_t)s*VO + r2] = v + p.fb[r2];
      }
    }
  }
}

extern "C" void kernel_launch(void* const* d_in, const int* in_sizes, int n_in,
                              void* d_out, int out_size, void* d_ws, size_t ws_size,
                              hipStream_t stream) {
  P p;
  p.x   = (const float*)d_in[0];
  p.y   = (const int*)  d_in[1];
  p.emb = (const float*)d_in[2];
  p.wih = (const float*)d_in[3];
  p.whh = (const float*)d_in[4];
  p.bih = (const float*)d_in[5];
  p.bhh = (const float*)d_in[6];
  p.cw  = (const float*)d_in[7];
  p.cb  = (const float*)d_in[8];
  p.aw  = (const float*)d_in[9];
  p.ab  = (const float*)d_in[10];
  p.fw  = (const float*)d_in[11];
  p.fb  = (const float*)d_in[12];
  p.out = (float*)d_out;
  p.ctrl = (int*)d_ws;
  // layout: 48KB ctrl | hx64 tagged 131,072B | fws floats | fp16 weights 3.67MB
  char* base = (char*)d_ws;
  p.hx64 = (ull*)(base + 49152);
  size_t flcount = (size_t)2*BB*AXP + 512 + (size_t)BB*8*HH;
  p.fws = (float*)(base + 49152 + 131072);
  p.w16 = (_Float16*)(base + 49152 + 131072 + 4*flcount);

  // zero ctrl + hx64 (stale tags from a previous launch alias exactly)
  hipMemsetAsync(d_ws, 0, 49152 + 131072, stream);

  void* args[] = { &p };
  hipError_t err = hipLaunchCooperativeKernel((const void*)seq2seq_kernel,
                                              dim3(NBLK), dim3(NTHR), args, 0, stream);
  if (err != hipSuccess) {
    seq2seq_kernel<<<dim3(NBLK), dim3(NTHR), 0, stream>>>(p);
  }
}